// Round 8
// baseline (2483.444 us; speedup 1.0000x reference)
//
#include <hip/hip_runtime.h>
#include <math.h>

#define TT 1024
#define BB 64
#define II 128
#define HH 256
#define OO 128
#define GPB 16           // blocks per group
#define NCOL 64          // gate-columns per block
#define Z_STRIDE 392     // padded z row stride per batch (floats)
#define PART_BG_STRIDE 68
#define PART_RC_STRIDE 273

// ws layout: flags 256 blocks x 16 ints (64B/block) = 16KB @0; abort @int 4096
// (byte 16384); hbuf [2][64][256] floats @float 8192 (byte 32768)
#define WS_HBUF_F 8192
#define WS_CLEAR_B 20480

__device__ __forceinline__ float rcp(float v) { return __builtin_amdgcn_rcpf(v); }
__device__ __forceinline__ float sigm(float v) { return rcp(1.f + __expf(-v)); }
__device__ __forceinline__ float ftanh(float v) {
    return __builtin_fmaf(-2.f, rcp(__expf(2.f * v) + 1.f), 1.f);
}

extern "C" __global__ void __launch_bounds__(256, 1) lstm_scan(
    const float* __restrict__ x, const float* __restrict__ W,
    const float* __restrict__ U, const float* __restrict__ bias,
    float* __restrict__ wsf)
{
    __shared__ float z[4 * Z_STRIDE];
    __shared__ float part[16 * PART_RC_STRIDE];
    __shared__ int   misc[8];

    int*   flags  = (int*)wsf;            // [block][wave] flag: block*16 + w*4
    int*   abortp = ((int*)wsf) + 4096;
    float* hbuf   = wsf + WS_HBUF_F;      // [2][64][256]

    const int tid  = threadIdx.x;
    const int gid  = blockIdx.x & 15;     // group
    const int p    = blockIdx.x >> 4;     // member: owns h-indices [16p,16p+16)
    const int cg   = tid & 15;            // column group (4 logical cols)
    const int rc   = tid >> 4;            // row group
    const int lane = tid & 63;
    const int w    = tid >> 6;            // wave index == batch slot in group
    const int myb  = 4 * gid + w;         // this wave's batch

    // ---- weights in VGPRs: wr[rr][i][c] = [W;U][rr*64+rc*4+i][cg*4+c]
    float wr[6][4][4];
    {
        const int c0 = cg * 4;
        const int gcol = (c0 >> 4) * HH + p * 16 + (c0 & 15);
#pragma unroll
        for (int rr = 0; rr < 6; ++rr) {
#pragma unroll
            for (int i = 0; i < 4; ++i) {
                const int r = rr * 64 + rc * 4 + i;
                const float4 wv = (rr < 2)
                    ? *(const float4*)(W + (size_t)r * 1024 + gcol)
                    : *(const float4*)(U + (size_t)(r - II) * 1024 + gcol);
                wr[rr][i][0] = wv.x; wr[rr][i][1] = wv.y;
                wr[rr][i][2] = wv.z; wr[rr][i][3] = wv.w;
            }
        }
    }
    // bias for this thread's reduce column (col = lane, same for all waves)
    const float bia_reg = bias[(lane >> 4) * HH + p * 16 + (lane & 15)];
    float creg = 0.f;                     // c-state: lane j<16 of wave w

    for (int idx = tid; idx < 4 * Z_STRIDE; idx += 256) z[idx] = 0.f;
    if (tid < 8) misc[tid] = 0;

    // ---- prologue: x_1 into z
    if (tid < 128) {
        const int b2 = tid >> 5, l2 = tid & 31;
        const float4 xv = *(const float4*)(
            x + ((size_t)(4 * gid + b2) * TT + 0) * II + 4 * l2);
        *(float4*)(z + b2 * Z_STRIDE + 4 * l2) = xv;
    }
    __syncthreads();

    for (int t = 1; t <= TT; ++t) {
        float acc[4][4];
#pragma unroll
        for (int a = 0; a < 4; ++a)
#pragma unroll
            for (int b = 0; b < 4; ++b) acc[a][b] = 0.f;

        // ---- matvec over x rows (rr 0..1): h-independent, before the wait
#pragma unroll
        for (int rr = 0; rr < 2; ++rr) {
#pragma unroll
            for (int bg = 0; bg < 4; ++bg) {
                const float4 zv = *(const float4*)(z + bg * Z_STRIDE + rr * 64 + rc * 4);
#pragma unroll
                for (int c = 0; c < 4; ++c)
                    acc[bg][c] += zv.x * wr[rr][0][c] + zv.y * wr[rr][1][c]
                                + zv.z * wr[rr][2][c] + zv.w * wr[rr][3][c];
            }
        }

        // ---- per-wave: poll the 16 member flags for THIS batch slot, then pull h
        if (t > 1) {
            const int need = t - 1;
            const int* fp = &flags[((lane & 15) * GPB + gid) * 16 + w * 4];
            int it = 0;
            for (;;) {
                int f1 = need, f2 = need;
                if (lane < GPB) {
                    f1 = __hip_atomic_load(fp, __ATOMIC_RELAXED, __HIP_MEMORY_SCOPE_AGENT);
                    f2 = __hip_atomic_load(fp, __ATOMIC_RELAXED, __HIP_MEMORY_SCOPE_AGENT);
                }
                if (__ballot(f1 >= need) == ~0ULL) break;
                if (__ballot(f2 >= need) == ~0ULL) break;
                if ((++it & 63) == 0) {
                    int abv = __hip_atomic_load(abortp, __ATOMIC_RELAXED,
                                                __HIP_MEMORY_SCOPE_AGENT);
                    if (abv) { if (lane == 0) misc[w] = 1; break; }
                    if (it > (1 << 19)) {
                        if (lane == 0) {
                            __hip_atomic_store(abortp, 1, __ATOMIC_RELAXED,
                                               __HIP_MEMORY_SCOPE_AGENT);
                            misc[w] = 1;
                        }
                        break;
                    }
                }
            }
            // h_{t-1}: 4 independent loads back-to-back (one round-trip)
            const float* hsrc = hbuf + ((size_t)((t - 1) & 1) * BB + myb) * HH;
            const float v0 = __hip_atomic_load(hsrc + lane,       __ATOMIC_RELAXED, __HIP_MEMORY_SCOPE_AGENT);
            const float v1 = __hip_atomic_load(hsrc + lane + 64,  __ATOMIC_RELAXED, __HIP_MEMORY_SCOPE_AGENT);
            const float v2 = __hip_atomic_load(hsrc + lane + 128, __ATOMIC_RELAXED, __HIP_MEMORY_SCOPE_AGENT);
            const float v3 = __hip_atomic_load(hsrc + lane + 192, __ATOMIC_RELAXED, __HIP_MEMORY_SCOPE_AGENT);
            float* zdst = z + w * Z_STRIDE + II + lane;
            zdst[0]   = v0;
            zdst[64]  = v1;
            zdst[128] = v2;
            zdst[192] = v3;
        }
        __syncthreads();                         // (1) all z h-parts written
        if (misc[0] | misc[1] | misc[2] | misc[3]) break;

        // ---- matvec over h rows (rr 2..5)
#pragma unroll
        for (int rr = 2; rr < 6; ++rr) {
#pragma unroll
            for (int bg = 0; bg < 4; ++bg) {
                const float4 zv = *(const float4*)(z + bg * Z_STRIDE + rr * 64 + rc * 4);
#pragma unroll
                for (int c = 0; c < 4; ++c)
                    acc[bg][c] += zv.x * wr[rr][0][c] + zv.y * wr[rr][1][c]
                                + zv.z * wr[rr][2][c] + zv.w * wr[rr][3][c];
            }
        }

        // ---- partials to LDS
#pragma unroll
        for (int bg = 0; bg < 4; ++bg)
#pragma unroll
            for (int c = 0; c < 4; ++c)
                part[rc * PART_RC_STRIDE + bg * PART_BG_STRIDE + cg * 4 + c] = acc[bg][c];
        __syncthreads();                         // (2) partials visible

        // ---- per-wave reduce (batch w, col = lane) + shfl-gates, no extra barrier
        float s = bia_reg;
#pragma unroll
        for (int r2 = 0; r2 < 16; ++r2)
            s += part[r2 * PART_RC_STRIDE + w * PART_BG_STRIDE + lane];

        const int j = lane & 15;
        const float sf = __shfl(s, j + 16);
        const float sg = __shfl(s, j + 32);
        const float so = __shfl(s, j + 48);
        if (lane < 16) {
            const float iv = sigm(s);
            const float fv = sigm(sf);
            const float gv = ftanh(sg);
            const float ov = sigm(so);
            creg = fv * creg + iv * gv;
            const float hv = ov * ftanh(creg);
            __hip_atomic_store(
                hbuf + ((size_t)(t & 1) * BB + myb) * HH + p * 16 + j,
                hv, __ATOMIC_RELAXED, __HIP_MEMORY_SCOPE_AGENT);
        }
        // drain ONLY this wave's h stores, then publish this wave's flag
        asm volatile("s_waitcnt vmcnt(0)" ::: "memory");
        if (lane == 0)
            __hip_atomic_store(&flags[blockIdx.x * 16 + w * 4], t,
                               __ATOMIC_RELAXED, __HIP_MEMORY_SCOPE_AGENT);

        // x_{t+1} prefetch for this wave's batch (after drain: off the flag path)
        if (t < TT && lane >= 16 && lane < 48) {
            const int l2 = lane - 16;
            const float4 xv = *(const float4*)(
                x + ((size_t)myb * TT + t) * II + 4 * l2);
            *(float4*)(z + w * Z_STRIDE + 4 * l2) = xv;
        }
        __syncthreads();                         // (3) x_{t+1} in z for all batches
    }
}

extern "C" __global__ void __launch_bounds__(256) lstm_out(
    const float* __restrict__ wsf, const float* __restrict__ dw,
    const float* __restrict__ db, float* __restrict__ out)
{
    __shared__ float hs[256];
    __shared__ float red[256];
    const int b = blockIdx.x;
    const int tid = threadIdx.x;
    const float* h0 = wsf + WS_HBUF_F;   // parity 0 holds h_{1024}
    hs[tid] = h0[(size_t)b * HH + tid];
    __syncthreads();
    const int o = tid & 127, half = tid >> 7;
    const float* wrow = dw + o * HH + half * 128;
    const float* hrow = hs + half * 128;
    float s = 0.f;
#pragma unroll
    for (int k = 0; k < 128; k += 4) {
        const float4 wv = *(const float4*)(wrow + k);
        s += hrow[k] * wv.x + hrow[k + 1] * wv.y + hrow[k + 2] * wv.z + hrow[k + 3] * wv.w;
    }
    red[tid] = s;
    __syncthreads();
    if (tid < 128)
        out[(size_t)b * OO + tid] = red[tid] + red[128 + tid] + db[tid];
}

extern "C" void kernel_launch(void* const* d_in, const int* in_sizes, int n_in,
                              void* d_out, int out_size, void* d_ws, size_t ws_size,
                              hipStream_t stream)
{
    const float* x    = (const float*)d_in[0];
    const float* W    = (const float*)d_in[1];
    const float* U    = (const float*)d_in[2];
    const float* bias = (const float*)d_in[3];
    const float* dw   = (const float*)d_in[4];
    const float* db   = (const float*)d_in[5];
    float* out = (float*)d_out;
    float* ws  = (float*)d_ws;

    // zero flags + abort each call (monotone protocol restarts cleanly per replay)
    hipMemsetAsync(d_ws, 0, WS_CLEAR_B, stream);
    hipLaunchKernelGGL(lstm_scan, dim3(256), dim3(256), 0, stream,
                       x, W, U, bias, ws);
    hipLaunchKernelGGL(lstm_out, dim3(64), dim3(256), 0, stream, ws, dw, db, out);
}